// Round 1
// baseline (1661.030 us; speedup 1.0000x reference)
//
#include <hip/hip_runtime.h>
#include <hip/hip_bf16.h>
#include <math.h>

// Performer attention (FAVOR+), B=64, N=2048, d=64, m=266, fp32.
// Round 1: correctness-first fp32 VALU implementation.
//   K1: global max over k-dash (sortable-uint atomicMax)
//   K2: kp = exp(dash - norm - gmax) + EPS ; accumulate k_cumsum + context
//   K3: qp (per-row max) ; D = qp.kcum ; out = (qp @ ctx) * 1/D
// NOTE: ratio = m^-0.5 cancels exactly in the output (scales qp,kp uniformly
// including the EPS term) -> omitted everywhere.

#define BATCH 64
#define SEQ   2048
#define DH    64
#define NF    266
#define NF2   272          // padded feature dim (16B-friendly)
#define NORMALIZER 0.35355339059327379f   // 64^-0.25
#define NORM_SCALE 0.0625f                // 0.5 * 64^-0.5
#define EPS_F 1e-4f

#define WS_KCUM_OFF 256
#define WS_CTX_OFF  (WS_KCUM_OFF + BATCH*NF2*4)          // 69888
#define WS_TOTAL    (WS_CTX_OFF + BATCH*NF2*DH*4)        // ~4.53 MB

__device__ __forceinline__ unsigned enc_f32(float f){
    unsigned u = __float_as_uint(f);
    return (u & 0x80000000u) ? ~u : (u | 0x80000000u);
}
__device__ __forceinline__ float dec_f32(unsigned u){
    return __uint_as_float((u & 0x80000000u) ? (u ^ 0x80000000u) : ~u);
}

// ---------------- K1: global max over k-dash --------------------------------
__global__ __launch_bounds__(256) void k1_kmax(const float* __restrict__ kin,
                                               const float* __restrict__ proj,
                                               unsigned* __restrict__ gmax)
{
    __shared__ float sP[64][137];   // projT half, scaled by NORMALIZER
    __shared__ float sK[64][68];    // 64 rows of k
    __shared__ float red[4];
    const int tid = threadIdx.x;
    const long long row0 = (long long)blockIdx.x * 64;

    for (int i = tid; i < 64*64; i += 256){
        sK[i >> 6][i & 63] = kin[row0*64 + i];
    }
    float lmax = -1e30f;
    #pragma unroll
    for (int h = 0; h < 2; ++h){
        const int f0 = h * 136;
        __syncthreads();
        for (int i = tid; i < 136*64; i += 256){
            int j = i & 63, f = i >> 6;
            int fgl = f0 + f;
            sP[j][f] = (fgl < NF) ? proj[fgl*64 + j] * NORMALIZER : 0.f;
        }
        __syncthreads();
        // 16 row-groups x 136 features; each item does 4 rows
        for (int i = tid; i < 16*136; i += 256){
            int f = i % 136, rq = i / 136;
            float d0=0.f, d1=0.f, d2=0.f, d3=0.f;
            #pragma unroll
            for (int j = 0; j < 64; ++j){
                float p = sP[j][f];
                d0 += sK[rq     ][j] * p;
                d1 += sK[rq + 16][j] * p;
                d2 += sK[rq + 32][j] * p;
                d3 += sK[rq + 48][j] * p;
            }
            if (f0 + f < NF)
                lmax = fmaxf(lmax, fmaxf(fmaxf(d0, d1), fmaxf(d2, d3)));
        }
    }
    #pragma unroll
    for (int off = 32; off; off >>= 1)
        lmax = fmaxf(lmax, __shfl_xor(lmax, off));
    if ((tid & 63) == 0) red[tid >> 6] = lmax;
    __syncthreads();
    if (tid == 0){
        float m = fmaxf(fmaxf(red[0], red[1]), fmaxf(red[2], red[3]));
        atomicMax(gmax, enc_f32(m));
    }
}

// ---------------- K2: kp, k_cumsum, context ---------------------------------
// grid: (chunk=9, split=4, b=64). Block owns feature-chunk of 32, 512 rows.
__global__ __launch_bounds__(256) void k2_ctx(const float* __restrict__ kin,
                                              const float* __restrict__ vin,
                                              const float* __restrict__ proj,
                                              const unsigned* __restrict__ gmaxp,
                                              float* __restrict__ kcum,
                                              float* __restrict__ ctx)
{
    __shared__ float sPc[64][33];
    __shared__ float sK[32][68];
    __shared__ float sV[32][68];
    __shared__ float kpL[32][33];
    __shared__ float nrm[32];
    const int tid   = threadIdx.x;
    const int chunk = blockIdx.x;          // 0..8
    const int split = blockIdx.y;          // 0..3
    const int b     = blockIdx.z;
    const int fl = tid & 31;
    const int eg = tid >> 5;               // 0..7
    const int e0 = eg * 8;
    const int fg = chunk * 32 + fl;        // global feature

    for (int i = tid; i < 64*32; i += 256){
        int j = i & 63, f = i >> 6;
        int fgl = chunk * 32 + f;
        sPc[j][f] = (fgl < NF) ? proj[fgl*64 + j] * NORMALIZER : 0.f;
    }
    const float gmax = dec_f32(*gmaxp);
    float acc[8];
    #pragma unroll
    for (int i = 0; i < 8; ++i) acc[i] = 0.f;
    float ksum = 0.f;

    const int nrows = SEQ / 4;             // 512
    const long long base = (long long)b * SEQ + (long long)split * nrows;
    for (int t = 0; t < nrows / 32; ++t){
        const long long rowb = base + t * 32;
        __syncthreads();
        for (int i = tid; i < 32*64; i += 256){
            int r = i >> 6, j = i & 63;
            sK[r][j] = kin[rowb*64 + i];
            sV[r][j] = vin[rowb*64 + i];
        }
        __syncthreads();
        if (tid < 32){
            float s = 0.f;
            #pragma unroll
            for (int j = 0; j < 64; ++j) s += sK[tid][j] * sK[tid][j];
            nrm[tid] = s * NORM_SCALE;
        }
        __syncthreads();
        {   // dash + kp for rows eg, eg+8, eg+16, eg+24 at feature fl
            float d0=0.f, d1=0.f, d2=0.f, d3=0.f;
            #pragma unroll
            for (int j = 0; j < 64; ++j){
                float p = sPc[j][fl];
                d0 += sK[eg     ][j] * p;
                d1 += sK[eg +  8][j] * p;
                d2 += sK[eg + 16][j] * p;
                d3 += sK[eg + 24][j] * p;
            }
            const bool live = (fg < NF);
            kpL[eg     ][fl] = live ? (__expf(d0 - nrm[eg     ] - gmax) + EPS_F) : 0.f;
            kpL[eg +  8][fl] = live ? (__expf(d1 - nrm[eg +  8] - gmax) + EPS_F) : 0.f;
            kpL[eg + 16][fl] = live ? (__expf(d2 - nrm[eg + 16] - gmax) + EPS_F) : 0.f;
            kpL[eg + 24][fl] = live ? (__expf(d3 - nrm[eg + 24] - gmax) + EPS_F) : 0.f;
        }
        __syncthreads();
        #pragma unroll 8
        for (int r = 0; r < 32; ++r){
            float kpv = kpL[r][fl];
            if (eg == 0) ksum += kpv;
            float4 va = *(const float4*)&sV[r][e0];
            float4 vb = *(const float4*)&sV[r][e0 + 4];
            acc[0] += kpv * va.x; acc[1] += kpv * va.y;
            acc[2] += kpv * va.z; acc[3] += kpv * va.w;
            acc[4] += kpv * vb.x; acc[5] += kpv * vb.y;
            acc[6] += kpv * vb.z; acc[7] += kpv * vb.w;
        }
    }
    if (fg < NF){
        if (eg == 0) atomicAdd(&kcum[b*NF2 + fg], ksum);
        float* cbase = &ctx[((long long)b*NF2 + fg)*64 + e0];
        #pragma unroll
        for (int i = 0; i < 8; ++i) atomicAdd(&cbase[i], acc[i]);
    }
}

// ---------------- K3: qp, D, out --------------------------------------------
__global__ __launch_bounds__(256) void k3_out(const float* __restrict__ qin,
                                              const float* __restrict__ proj,
                                              const float* __restrict__ kcum,
                                              const float* __restrict__ ctx,
                                              float* __restrict__ out)
{
    __shared__ float sP[64][137];
    __shared__ float dsh[2][16][137];
    __shared__ float sQ[16][68];
    __shared__ float nrm[16], mxr[16], dnv[16];
    __shared__ float kcumL[NF2];
    const int tid = threadIdx.x;
    const long long row0 = (long long)blockIdx.x * 16;
    const int b = blockIdx.x >> 7;         // 2048/16 = 128 blocks per batch

    for (int i = tid; i < 16*64; i += 256)
        sQ[i >> 6][i & 63] = qin[row0*64 + i];
    for (int i = tid; i < NF2; i += 256)
        kcumL[i] = kcum[b*NF2 + i];
    __syncthreads();
    if (tid < 16){
        float s = 0.f;
        #pragma unroll
        for (int j = 0; j < 64; ++j) s += sQ[tid][j] * sQ[tid][j];
        nrm[tid] = s * NORM_SCALE;
    }
    #pragma unroll
    for (int h = 0; h < 2; ++h){
        const int f0 = h * 136;
        __syncthreads();
        for (int i = tid; i < 136*64; i += 256){
            int j = i & 63, f = i >> 6;
            int fgl = f0 + f;
            sP[j][f] = (fgl < NF) ? proj[fgl*64 + j] * NORMALIZER : 0.f;
        }
        __syncthreads();
        for (int i = tid; i < 4*136; i += 256){
            int f = i % 136, rq = i / 136;   // rows rq, rq+4, rq+8, rq+12
            float d0=0.f, d1=0.f, d2=0.f, d3=0.f;
            #pragma unroll
            for (int j = 0; j < 64; ++j){
                float p = sP[j][f];
                d0 += sQ[rq     ][j] * p;
                d1 += sQ[rq +  4][j] * p;
                d2 += sQ[rq +  8][j] * p;
                d3 += sQ[rq + 12][j] * p;
            }
            dsh[h][rq     ][f] = d0;
            dsh[h][rq +  4][f] = d1;
            dsh[h][rq +  8][f] = d2;
            dsh[h][rq + 12][f] = d3;
        }
    }
    __syncthreads();
    const int r  = tid >> 4;
    const int li = tid & 15;
    {   // per-row max over real features
        float m = -1e30f;
        for (int f = li; f < NF; f += 16){
            int hh = (f >= 136) ? 1 : 0;
            m = fmaxf(m, dsh[hh][r][f - 136*hh]);
        }
        #pragma unroll
        for (int off = 8; off; off >>= 1) m = fmaxf(m, __shfl_xor(m, off));
        if (li == 0) mxr[r] = m;
    }
    __syncthreads();
    for (int i = tid; i < 16*NF2; i += 256){   // qp in place (pad -> 0)
        int rr = i / NF2, f = i % NF2;
        int hh = (f >= 136) ? 1 : 0;
        int flx = f - 136*hh;
        float v = dsh[hh][rr][flx];
        dsh[hh][rr][flx] = (f < NF) ? (__expf(v - nrm[rr] - mxr[rr]) + EPS_F) : 0.f;
    }
    __syncthreads();
    {   // D per row
        float s = 0.f;
        for (int f = li; f < NF; f += 16){
            int hh = (f >= 136) ? 1 : 0;
            s += dsh[hh][r][f - 136*hh] * kcumL[f];
        }
        #pragma unroll
        for (int off = 8; off; off >>= 1) s += __shfl_xor(s, off);
        if (li == 0) dnv[r] = 1.f / s;
    }
    __syncthreads();
    {   // out[r][e0..e0+3]
        const int e0 = li * 4;
        float o0=0.f, o1=0.f, o2=0.f, o3=0.f;
        const float* cb = &ctx[(long long)b * NF2 * 64];
        for (int f = 0; f < NF; ++f){
            int hh = (f >= 136) ? 1 : 0;
            float qv = dsh[hh][r][f - 136*hh];
            float4 c = *(const float4*)&cb[f*64 + e0];
            o0 += qv * c.x; o1 += qv * c.y; o2 += qv * c.z; o3 += qv * c.w;
        }
        float dv = dnv[r];
        float4 res = make_float4(o0*dv, o1*dv, o2*dv, o3*dv);
        *(float4*)&out[(row0 + r)*64 + e0] = res;
    }
}

extern "C" void kernel_launch(void* const* d_in, const int* in_sizes, int n_in,
                              void* d_out, int out_size, void* d_ws, size_t ws_size,
                              hipStream_t stream)
{
    const float* q    = (const float*)d_in[0];
    const float* k    = (const float*)d_in[1];
    const float* v    = (const float*)d_in[2];
    const float* proj = (const float*)d_in[3];
    float* out = (float*)d_out;

    unsigned* gmax = (unsigned*)d_ws;
    float* kcum = (float*)((char*)d_ws + WS_KCUM_OFF);
    float* ctx  = (float*)((char*)d_ws + WS_CTX_OFF);

    hipMemsetAsync(d_ws, 0, WS_TOTAL, stream);
    k1_kmax<<<dim3((BATCH*SEQ)/64), 256, 0, stream>>>(k, proj, gmax);
    k2_ctx<<<dim3(9, 4, BATCH), 256, 0, stream>>>(k, v, proj, gmax, kcum, ctx);
    k3_out<<<dim3((BATCH*SEQ)/16), 256, 0, stream>>>(q, proj, kcum, ctx, out);
}

// Round 2
// 368.114 us; speedup vs baseline: 4.5123x; 4.5123x over previous
//
#include <hip/hip_runtime.h>
#include <math.h>

// Performer attention (FAVOR+), B=64, N=2048, d=64, m=266, fp32 in/out.
// Round 2: split-bf16 MFMA (hi/lo, 3-mfma products) for all contractions.
//   prep_proj: proj * 64^-0.25 -> B-frag layout (hi/lo bf16) in ws
//   k1_kmax : dash = K @ projT via MFMA, global max -> atomicMax (sortable uint)
//   k2_ctx  : dash -> kp=exp(dash-nrm-gmax)+eps ; kcum += ; ctx += kpT @ V (MFMA)
//   prep_ctx: ctx fp32 -> B-frag layout (hi/lo bf16) per batch
//   k3_out  : dash(Q) -> qp (per-row max) ; D = qp.kcum ; out = (qp @ ctx) * 1/D
// ratio = m^-0.5 cancels exactly in out (scales qp,kp incl. eps) -> omitted.

#define SEQ   2048
#define NF    266
#define NF2   288
#define NORMALIZER 0.35355339059327379f   // 64^-0.25
#define EPS_F 1e-4f

// ws layout (bytes)
#define WS_PROJFRAG 256                    // 17*2*2*1024 = 69632
#define WS_KCUM     69888                  // 64*288*4    = 73728
#define WS_CTX      143616                 // 64*288*64*4 = 4718592
#define WS_CTXFRAG  4862208                // 64*73728    = 4718592
#define WS_ZERO_BYTES 4862208

typedef __attribute__((ext_vector_type(8))) short bf16x8;
typedef __attribute__((ext_vector_type(4))) float f32x4;
#define MFMA(A,B,C) __builtin_amdgcn_mfma_f32_16x16x32_bf16(A,B,C,0,0,0)

__device__ __forceinline__ unsigned enc_f32(float f){
    unsigned u = __float_as_uint(f);
    return (u & 0x80000000u) ? ~u : (u | 0x80000000u);
}
__device__ __forceinline__ float dec_f32(unsigned u){
    return __uint_as_float((u & 0x80000000u) ? (u ^ 0x80000000u) : ~u);
}
__device__ __forceinline__ unsigned short f2bf(float x){   // RNE
    unsigned u = __float_as_uint(x);
    return (unsigned short)((u + 0x7FFFu + ((u >> 16) & 1u)) >> 16);
}
__device__ __forceinline__ float bf2f(unsigned short h){
    return __uint_as_float(((unsigned)h) << 16);
}
__device__ __forceinline__ void packhl(float4 x, float4 y, bf16x8& H, bf16x8& L){
    float v[8] = {x.x, x.y, x.z, x.w, y.x, y.y, y.z, y.w};
    #pragma unroll
    for (int i = 0; i < 8; ++i){
        unsigned short h = f2bf(v[i]);
        H[i] = (short)h;
        L[i] = (short)f2bf(v[i] - bf2f(h));
    }
}

// ---------------- prep_proj: proj -> B-frag hi/lo layout --------------------
// frag idx = ((t*2 + kstep)*2 + h)*1024 + lane*16 ; value = NORM*proj[f][k]
// lane: f = t*16 + (l&15), k = kstep*32 + (l>>4)*8 + i
__global__ __launch_bounds__(64) void prep_proj(const float* __restrict__ proj,
                                                char* __restrict__ ws)
{
    const int t = blockIdx.x >> 1, s = blockIdx.x & 1, l = threadIdx.x;
    const int f = t*16 + (l & 15);
    const int k0 = s*32 + (l >> 4)*8;
    bf16x8 H, L;
    #pragma unroll
    for (int i = 0; i < 8; ++i){
        float v = (f < NF) ? proj[f*64 + k0 + i] * NORMALIZER : 0.f;
        unsigned short h = f2bf(v);
        H[i] = (short)h;
        L[i] = (short)f2bf(v - bf2f(h));
    }
    char* base = ws + WS_PROJFRAG + (size_t)((t*2 + s)*2)*1024 + l*16;
    *(bf16x8*)(base)        = H;
    *(bf16x8*)(base + 1024) = L;
}

// ---------------- K1: global max over k-dash (MFMA) -------------------------
__global__ __launch_bounds__(256) void k1_kmax(const float* __restrict__ kin,
                                               const char* __restrict__ ws,
                                               unsigned* __restrict__ gmax)
{
    __shared__ float red[4];
    const int tid = threadIdx.x, l = tid & 63, w = tid >> 6;
    const int fq = l & 15, lg = l >> 4;
    const long long rowb = (long long)blockIdx.x*64 + w*16;
    const float* rp = kin + (rowb + fq)*64 + lg*8;
    float4 a0 = *(const float4*)(rp);
    float4 a1 = *(const float4*)(rp + 4);
    float4 a2 = *(const float4*)(rp + 32);
    float4 a3 = *(const float4*)(rp + 36);
    bf16x8 Ah0, Al0, Ah1, Al1;
    packhl(a0, a1, Ah0, Al0);
    packhl(a2, a3, Ah1, Al1);
    const char* pf = ws + WS_PROJFRAG;
    float lmax = -3.0e38f;
    #pragma unroll
    for (int t = 0; t < 17; ++t){
        bf16x8 Bh0 = *(const bf16x8*)(pf + (size_t)((t*2+0)*2+0)*1024 + l*16);
        bf16x8 Bl0 = *(const bf16x8*)(pf + (size_t)((t*2+0)*2+1)*1024 + l*16);
        bf16x8 Bh1 = *(const bf16x8*)(pf + (size_t)((t*2+1)*2+0)*1024 + l*16);
        bf16x8 Bl1 = *(const bf16x8*)(pf + (size_t)((t*2+1)*2+1)*1024 + l*16);
        f32x4 d = {0.f, 0.f, 0.f, 0.f};
        d = MFMA(Ah0, Bh0, d); d = MFMA(Ah0, Bl0, d); d = MFMA(Al0, Bh0, d);
        d = MFMA(Ah1, Bh1, d); d = MFMA(Ah1, Bl1, d); d = MFMA(Al1, Bh1, d);
        if (t < 16 || fq < 10)
            lmax = fmaxf(lmax, fmaxf(fmaxf(d.x, d.y), fmaxf(d.z, d.w)));
    }
    #pragma unroll
    for (int off = 1; off < 64; off <<= 1)
        lmax = fmaxf(lmax, __shfl_xor(lmax, off));
    if (l == 0) red[w] = lmax;
    __syncthreads();
    if (tid == 0)
        atomicMax(gmax, enc_f32(fmaxf(fmaxf(red[0], red[1]), fmaxf(red[2], red[3]))));
}

// ---------------- K2: kp, kcum, ctx (MFMA, fused per f-tile) ----------------
// grid (split=8, b=64), 256 thr. Block: 256 rows = 4 chunks of 64.
__global__ __launch_bounds__(256, 2) void k2_ctx(const float* __restrict__ kin,
                                                 const float* __restrict__ vin,
                                                 char* __restrict__ ws)
{
    __shared__ __align__(16) char kpb[2][4096];
    __shared__ float nrmL[64];
    const int tid = threadIdx.x, l = tid & 63, w = tid >> 6;
    const int fq = l & 15, lg = l >> 4;
    const int split = blockIdx.x, b = blockIdx.y;
    const float gmax = dec_f32(*(const unsigned*)ws);
    const char* pf = ws + WS_PROJFRAG;
    float* kcum = (float*)(ws + WS_KCUM);
    float* ctx  = (float*)(ws + WS_CTX);
    const int e = w*16 + fq;
    const int sw = (fq & 7) << 4;

    f32x4 acc2[17];
    float kc[17];
    #pragma unroll
    for (int t = 0; t < 17; ++t){ acc2[t] = (f32x4){0.f,0.f,0.f,0.f}; kc[t] = 0.f; }

    for (int c = 0; c < 4; ++c){
        const long long rowc = (long long)b*SEQ + split*256 + c*64;
        // A-frags: K rows (wave-owned 16 rows)
        const float* rp = kin + (rowc + w*16 + fq)*64 + lg*8;
        float4 a0 = *(const float4*)(rp);
        float4 a1 = *(const float4*)(rp + 4);
        float4 a2 = *(const float4*)(rp + 32);
        float4 a3 = *(const float4*)(rp + 36);
        bf16x8 Ah0, Al0, Ah1, Al1;
        packhl(a0, a1, Ah0, Al0);
        packhl(a2, a3, Ah1, Al1);
        // row norms (0.0625 * sum k^2), reduce across lane-groups
        float np = a0.x*a0.x + a0.y*a0.y + a0.z*a0.z + a0.w*a0.w
                 + a1.x*a1.x + a1.y*a1.y + a1.z*a1.z + a1.w*a1.w
                 + a2.x*a2.x + a2.y*a2.y + a2.z*a2.z + a2.w*a2.w
                 + a3.x*a3.x + a3.y*a3.y + a3.z*a3.z + a3.w*a3.w;
        np += __shfl_xor(np, 16);
        np += __shfl_xor(np, 32);
        if (lg == 0) nrmL[w*16 + fq] = np * 0.0625f;
        // V B-frags for this wave's e-tile
        bf16x8 Vh0, Vl0, Vh1, Vl1;
        {
            float4 x, y;
            float vv[8];
            #pragma unroll
            for (int i = 0; i < 8; ++i) vv[i] = vin[(rowc + lg*8 + i)*64 + e];
            x = make_float4(vv[0],vv[1],vv[2],vv[3]); y = make_float4(vv[4],vv[5],vv[6],vv[7]);
            packhl(x, y, Vh0, Vl0);
            #pragma unroll
            for (int i = 0; i < 8; ++i) vv[i] = vin[(rowc + 32 + lg*8 + i)*64 + e];
            x = make_float4(vv[0],vv[1],vv[2],vv[3]); y = make_float4(vv[4],vv[5],vv[6],vv[7]);
            packhl(x, y, Vh1, Vl1);
        }
        #pragma unroll
        for (int t = 0; t < 17; ++t){
            // GEMM1: dash tile t
            bf16x8 Bh0 = *(const bf16x8*)(pf + (size_t)((t*2+0)*2+0)*1024 + l*16);
            bf16x8 Bl0 = *(const bf16x8*)(pf + (size_t)((t*2+0)*2+1)*1024 + l*16);
            bf16x8 Bh1 = *(const bf16x8*)(pf + (size_t)((t*2+1)*2+0)*1024 + l*16);
            bf16x8 Bl1 = *(const bf16x8*)(pf + (size_t)((t*2+1)*2+1)*1024 + l*16);
            f32x4 d = {0.f, 0.f, 0.f, 0.f};
            d = MFMA(Ah0, Bh0, d); d = MFMA(Ah0, Bl0, d); d = MFMA(Al0, Bh0, d);
            d = MFMA(Ah1, Bh1, d); d = MFMA(Ah1, Bl1, d); d = MFMA(Al1, Bh1, d);
            // kp = exp(dash - nrm - gmax) + eps  (masked beyond f=266)
            float4 nr4 = *(float4*)&nrmL[w*16 + lg*4];
            const bool fv = (t < 16) || (fq < 10);
            float kp0 = fv ? (__expf(d.x - nr4.x - gmax) + EPS_F) : 0.f;
            float kp1 = fv ? (__expf(d.y - nr4.y - gmax) + EPS_F) : 0.f;
            float kp2 = fv ? (__expf(d.z - nr4.z - gmax) + EPS_F) : 0.f;
            float kp3 = fv ? (__expf(d.w - nr4.w - gmax) + EPS_F) : 0.f;
            kc[t] += kp0 + kp1 + kp2 + kp3;
            unsigned short h0 = f2bf(kp0), h1 = f2bf(kp1), h2 = f2bf(kp2), h3 = f2bf(kp3);
            unsigned short o0 = f2bf(kp0 - bf2f(h0)), o1 = f2bf(kp1 - bf2f(h1));
            unsigned short o2 = f2bf(kp2 - bf2f(h2)), o3 = f2bf(kp3 - bf2f(h3));
            char* bufw = kpb[t & 1];
            const int off = w*32 + lg*8;
            *(uint2*)(bufw + fq*256 + ((off      ) ^ sw)) = make_uint2((unsigned)h0 | ((unsigned)h1<<16), (unsigned)h2 | ((unsigned)h3<<16));
            *(uint2*)(bufw + fq*256 + ((off + 128) ^ sw)) = make_uint2((unsigned)o0 | ((unsigned)o1<<16), (unsigned)o2 | ((unsigned)o3<<16));
            // GEMM2: ctx tile t-1 (kpT @ V) from the other buffer
            if (t > 0){
                const char* bufr = kpb[(t-1) & 1];
                bf16x8 Kh0 = *(const bf16x8*)(bufr + fq*256 + ((lg*16      ) ^ sw));
                bf16x8 Kh1 = *(const bf16x8*)(bufr + fq*256 + ((lg*16 +  64) ^ sw));
                bf16x8 Kl0 = *(const bf16x8*)(bufr + fq*256 + ((lg*16 + 128) ^ sw));
                bf16x8 Kl1 = *(const bf16x8*)(bufr + fq*256 + ((lg*16 + 192) ^ sw));
                f32x4 a = acc2[t-1];
                a = MFMA(Kh0, Vh0, a); a = MFMA(Kh0, Vl0, a); a = MFMA(Kl0, Vh0, a);
                a = MFMA(Kh1, Vh1, a); a = MFMA(Kh1, Vl1, a); a = MFMA(Kl1, Vh1, a);
                acc2[t-1] = a;
            }
            __syncthreads();
        }
        {   // epilogue: GEMM2 tile 16 (buffer 0)
            const char* bufr = kpb[0];
            bf16x8 Kh0 = *(const bf16x8*)(bufr + fq*256 + ((lg*16      ) ^ sw));
            bf16x8 Kh1 = *(const bf16x8*)(bufr + fq*256 + ((lg*16 +  64) ^ sw));
            bf16x8 Kl0 = *(const bf16x8*)(bufr + fq*256 + ((lg*16 + 128) ^ sw));
            bf16x8 Kl1 = *(const bf16x8*)(bufr + fq*256 + ((lg*16 + 192) ^ sw));
            f32x4 a = acc2[16];
            a = MFMA(Kh0, Vh0, a); a = MFMA(Kh0, Vl0, a); a = MFMA(Kl0, Vh0, a);
            a = MFMA(Kh1, Vh1, a); a = MFMA(Kh1, Vl1, a); a = MFMA(Kl1, Vh1, a);
            acc2[16] = a;
        }
        __syncthreads();
    }
    // flush kcum + ctx
    #pragma unroll
    for (int t = 0; t < 17; ++t){
        float s = kc[t];
        s += __shfl_xor(s, 16);
        s += __shfl_xor(s, 32);
        const int f = t*16 + fq;
        if (lg == 0 && f < NF) atomicAdd(&kcum[b*NF2 + f], s);
        const int fr = t*16 + lg*4;
        if (fr + 0 < NF) atomicAdd(&ctx[((size_t)b*NF2 + fr + 0)*64 + e], acc2[t].x);
        if (fr + 1 < NF) atomicAdd(&ctx[((size_t)b*NF2 + fr + 1)*64 + e], acc2[t].y);
        if (fr + 2 < NF) atomicAdd(&ctx[((size_t)b*NF2 + fr + 2)*64 + e], acc2[t].z);
        if (fr + 3 < NF) atomicAdd(&ctx[((size_t)b*NF2 + fr + 3)*64 + e], acc2[t].w);
    }
}

// ---------------- prep_ctx: ctx fp32 -> B-frag hi/lo layout -----------------
// per (b, nt, ks): lane: e = nt*16 + (l&15), f = ks*32 + (l>>4)*8 + i
__global__ __launch_bounds__(64) void prep_ctx(char* __restrict__ ws)
{
    const int b = blockIdx.x / 36, r = blockIdx.x % 36, nt = r / 9, ks = r % 9;
    const int l = threadIdx.x;
    const float* ctx = (const float*)(ws + WS_CTX) + (size_t)b*NF2*64;
    const int e = nt*16 + (l & 15);
    const int f0 = ks*32 + (l >> 4)*8;
    bf16x8 H, L;
    #pragma unroll
    for (int i = 0; i < 8; ++i){
        float v = ctx[(size_t)(f0 + i)*64 + e];
        unsigned short h = f2bf(v);
        H[i] = (short)h;
        L[i] = (short)f2bf(v - bf2f(h));
    }
    char* base = ws + WS_CTXFRAG + (size_t)b*73728 + nt*18432 + ks*2048 + l*16;
    *(bf16x8*)(base)        = H;
    *(bf16x8*)(base + 1024) = L;
}

// ---------------- K3: qp, D, out (MFMA) -------------------------------------
// grid 2048, 256 thr; block = 64 q rows (4 waves x 16), hi/lo two GEMM passes.
__global__ __launch_bounds__(256, 2) void k3_out(const float* __restrict__ qin,
                                                 const char* __restrict__ ws,
                                                 float* __restrict__ out)
{
    __shared__ __align__(16) char qpb[64*592];   // [64 rows][296 bf16], pad stride
    __shared__ float nrmL[64];
    __shared__ float kcumL[NF2];
    const int tid = threadIdx.x, l = tid & 63, w = tid >> 6;
    const int fq = l & 15, lg = l >> 4;
    const int b = blockIdx.x >> 5;
    const long long rowb = (long long)blockIdx.x*64;
    const char* pf = ws + WS_PROJFRAG;
    const char* cf = ws + WS_CTXFRAG + (size_t)b*73728;
    const float* kcum = (const float*)(ws + WS_KCUM) + (size_t)b*NF2;

    for (int i = tid; i < NF2; i += 256) kcumL[i] = kcum[i];
    for (int i = tid; i < 64*16; i += 256){           // zero pad f in [272,288)
        int rr = i >> 4;
        *(short*)(qpb + (size_t)rr*592 + (272 + (i & 15))*2) = 0;
    }
    // A-frags: Q rows + norms
    const float* rp = qin + (rowb + w*16 + fq)*64 + lg*8;
    float4 a0 = *(const float4*)(rp);
    float4 a1 = *(const float4*)(rp + 4);
    float4 a2 = *(const float4*)(rp + 32);
    float4 a3 = *(const float4*)(rp + 36);
    bf16x8 Ah0, Al0, Ah1, Al1;
    packhl(a0, a1, Ah0, Al0);
    packhl(a2, a3, Ah1, Al1);
    float np = a0.x*a0.x + a0.y*a0.y + a0.z*a0.z + a0.w*a0.w
             + a1.x*a1.x + a1.y*a1.y + a1.z*a1.z + a1.w*a1.w
             + a2.x*a2.x + a2.y*a2.y + a2.z*a2.z + a2.w*a2.w
             + a3.x*a3.x + a3.y*a3.y + a3.z*a3.z + a3.w*a3.w;
    np += __shfl_xor(np, 16);
    np += __shfl_xor(np, 32);
    if (lg == 0) nrmL[w*16 + fq] = np * 0.0625f;
    __syncthreads();
    // dash for all 17 f-tiles (kept in registers)
    f32x4 p[17];
    #pragma unroll
    for (int t = 0; t < 17; ++t){
        bf16x8 Bh0 = *(const bf16x8*)(pf + (size_t)((t*2+0)*2+0)*1024 + l*16);
        bf16x8 Bl0 = *(const bf16x8*)(pf + (size_t)((t*2+0)*2+1)*1024 + l*16);
        bf16x8 Bh1 = *(const bf16x8*)(pf + (size_t)((t*2+1)*2+0)*1024 + l*16);
        bf16x8 Bl1 = *(const bf16x8*)(pf + (size_t)((t*2+1)*2+1)*1024 + l*16);
        f32x4 d = {0.f, 0.f, 0.f, 0.f};
        d = MFMA(Ah0, Bh0, d); d = MFMA(Ah0, Bl0, d); d = MFMA(Al0, Bh0, d);
        d = MFMA(Ah1, Bh1, d); d = MFMA(Ah1, Bl1, d); d = MFMA(Al1, Bh1, d);
        p[t] = d;
    }
    // per-row max (over real features)
    float mx0 = -3.0e38f, mx1 = -3.0e38f, mx2 = -3.0e38f, mx3 = -3.0e38f;
    #pragma unroll
    for (int t = 0; t < 17; ++t){
        if (t < 16 || fq < 10){
            mx0 = fmaxf(mx0, p[t].x); mx1 = fmaxf(mx1, p[t].y);
            mx2 = fmaxf(mx2, p[t].z); mx3 = fmaxf(mx3, p[t].w);
        }
    }
    #pragma unroll
    for (int off = 1; off < 16; off <<= 1){
        mx0 = fmaxf(mx0, __shfl_xor(mx0, off));
        mx1 = fmaxf(mx1, __shfl_xor(mx1, off));
        mx2 = fmaxf(mx2, __shfl_xor(mx2, off));
        mx3 = fmaxf(mx3, __shfl_xor(mx3, off));
    }
    // qp = exp(dash - nrm - rowmax) + eps ; D = qp . kcum
    float4 nr4 = *(float4*)&nrmL[w*16 + lg*4];
    float d0 = 0.f, d1 = 0.f, d2 = 0.f, d3 = 0.f;
    #pragma unroll
    for (int t = 0; t < 17; ++t){
        const bool fv = (t < 16) || (fq < 10);
        float q0 = fv ? (__expf(p[t].x - nr4.x - mx0) + EPS_F) : 0.f;
        float q1 = fv ? (__expf(p[t].y - nr4.y - mx1) + EPS_F) : 0.f;
        float q2 = fv ? (__expf(p[t].z - nr4.z - mx2) + EPS_F) : 0.f;
        float q3 = fv ? (__expf(p[t].w - nr4.w - mx3) + EPS_F) : 0.f;
        const float kcv = kcumL[t*16 + fq];
        d0 += q0*kcv; d1 += q1*kcv; d2 += q2*kcv; d3 += q3*kcv;
        p[t].x = q0; p[t].y = q1; p[t].z = q2; p[t].w = q3;
    }
    #pragma unroll
    for (int off = 1; off < 16; off <<= 1){
        d0 += __shfl_xor(d0, off); d1 += __shfl_xor(d1, off);
        d2 += __shfl_xor(d2, off); d3 += __shfl_xor(d3, off);
    }
    const float iv0 = 1.f/d0, iv1 = 1.f/d1, iv2 = 1.f/d2, iv3 = 1.f/d3;
    // write qp_hi (wave-local rows), pass-hi
    #pragma unroll
    for (int t = 0; t < 17; ++t){
        const int fb = (t*16 + fq)*2;
        *(short*)(qpb + (size_t)(w*16 + lg*4 + 0)*592 + fb) = (short)f2bf(p[t].x);
        *(short*)(qpb + (size_t)(w*16 + lg*4 + 1)*592 + fb) = (short)f2bf(p[t].y);
        *(short*)(qpb + (size_t)(w*16 + lg*4 + 2)*592 + fb) = (short)f2bf(p[t].z);
        *(short*)(qpb + (size_t)(w*16 + lg*4 + 3)*592 + fb) = (short)f2bf(p[t].w);
    }
    __syncthreads();
    f32x4 o[4];
    #pragma unroll
    for (int nt = 0; nt < 4; ++nt) o[nt] = (f32x4){0.f,0.f,0.f,0.f};
    #pragma unroll
    for (int ks = 0; ks < 9; ++ks){
        bf16x8 Ah = *(const bf16x8*)(qpb + (size_t)(w*16 + fq)*592 + ks*64 + lg*16);
        #pragma unroll
        for (int nt = 0; nt < 4; ++nt){
            bf16x8 Bh = *(const bf16x8*)(cf + nt*18432 + ks*2048 + l*16);
            bf16x8 Bl = *(const bf16x8*)(cf + nt*18432 + ks*2048 + 1024 + l*16);
            o[nt] = MFMA(Ah, Bh, o[nt]);
            o[nt] = MFMA(Ah, Bl, o[nt]);
        }
    }
    __syncthreads();
    // write qp_lo, pass-lo
    #pragma unroll
    for (int t = 0; t < 17; ++t){
        const int fb = (t*16 + fq)*2;
        unsigned short h;
        h = f2bf(p[t].x); *(short*)(qpb + (size_t)(w*16 + lg*4 + 0)*592 + fb) = (short)f2bf(p[t].x - bf2f(h));
        h = f2bf(p[t].y); *(short*)(qpb + (size_t)(w*16 + lg*4 + 1)*592 + fb) = (short)f2bf(p[t].y - bf2f(h));
        h = f2bf(p[t].z); *(short*)(qpb + (size_t)(w*16 + lg*4 + 2)*592 + fb) = (short)f2bf(p[t].z - bf2f(h));
        h = f2bf(p[t].w); *(short*)(qpb + (size_t)(w*16 + lg*4 + 3)*592 + fb) = (short)f2bf(p[t].w - bf2f(h));
    }
    __syncthreads();
    #pragma unroll
    for (int ks = 0; ks < 9; ++ks){
        bf16x8 Al = *(const bf16x8*)(qpb + (size_t)(w*16 + fq)*592 + ks*64 + lg*16);
        #pragma unroll
        for (int nt = 0; nt < 4; ++nt){
            bf16x8 Bh = *(const bf16x8*)(cf + nt*18432 + ks*2048 + l*16);
            o[nt] = MFMA(Al, Bh, o[nt]);
        }
    }
    // store out = o * Dinv
    #pragma unroll
    for (int nt = 0; nt < 4; ++nt){
        const size_t rb = (size_t)(rowb + w*16 + lg*4);
        out[(rb + 0)*64 + nt*16 + fq] = o[nt].x * iv0;
        out[(rb + 1)*64 + nt*16 + fq] = o[nt].y * iv1;
        out[(rb + 2)*64 + nt*16 + fq] = o[nt].z * iv2;
        out[(rb + 3)*64 + nt*16 + fq] = o[nt].w * iv3;
    }
}

extern "C" void kernel_launch(void* const* d_in, const int* in_sizes, int n_in,
                              void* d_out, int out_size, void* d_ws, size_t ws_size,
                              hipStream_t stream)
{
    const float* q    = (const float*)d_in[0];
    const float* k    = (const float*)d_in[1];
    const float* v    = (const float*)d_in[2];
    const float* proj = (const float*)d_in[3];
    float* out = (float*)d_out;
    char* ws = (char*)d_ws;

    hipMemsetAsync(ws, 0, WS_ZERO_BYTES, stream);
    prep_proj<<<34, 64, 0, stream>>>(proj, ws);
    k1_kmax<<<2048, 256, 0, stream>>>(k, ws, (unsigned*)ws);
    k2_ctx<<<dim3(8, 64), 256, 0, stream>>>(k, v, ws);
    prep_ctx<<<2304, 64, 0, stream>>>(ws);
    k3_out<<<2048, 256, 0, stream>>>(q, ws, out);
}

// Round 3
// 354.023 us; speedup vs baseline: 4.6919x; 1.0398x over previous
//
#include <hip/hip_runtime.h>
#include <math.h>

// Performer attention (FAVOR+), B=64, N=2048, d=64, m=266, fp32 in/out.
// Round 3:
//  - k1 eliminated: kp = e^{-gmax}*exp(dash-norm) + eps  => K-side pass needs
//    no gmax. k2 accumulates CtxE = sum exp(dash-norm)*v, KcumE, Sv = sum v,
//    and computes gmax as a byproduct (atomicMax). Compose happens later.
//  - k2 split 8->16 for occupancy (4 blocks/CU).
//  - k3 out-GEMM in fp16 (qp in [eps,1] fits f16 perfectly): single qp plane,
//    ctx as f16 hi+lo. Removes the qp-lo pass (2 barriers + 36 MFMA).
// ratio = m^-0.5 cancels exactly in out -> omitted.

#define SEQ   2048
#define NF    266
#define NF2   288
#define NORMALIZER 0.35355339059327379f   // 64^-0.25
#define EPS_F 1e-4f

// ws layout (bytes)
#define WS_PROJFRAG 256                    // 17*2*2*1024 = 69632 -> 69888
#define WS_KCUM     69888                  // 64*288*4    = 73728 -> 143616
#define WS_SV       143616                 // 64*64*4     = 16384 -> 160000
#define WS_CTX      160000                 // 64*288*64*4 = 4718592 -> 4878592
#define WS_CTXFRAG  4878592                // 64*73728    = 4718592 -> 9597184
#define WS_ZERO_BYTES 4878592

typedef __attribute__((ext_vector_type(8))) short bf16x8;
typedef __attribute__((ext_vector_type(8))) _Float16 f16x8;
typedef __attribute__((ext_vector_type(4))) float f32x4;
#define MFMA(A,B,C)  __builtin_amdgcn_mfma_f32_16x16x32_bf16(A,B,C,0,0,0)
#define MFMAH(A,B,C) __builtin_amdgcn_mfma_f32_16x16x32_f16(A,B,C,0,0,0)

__device__ __forceinline__ unsigned enc_f32(float f){
    unsigned u = __float_as_uint(f);
    return (u & 0x80000000u) ? ~u : (u | 0x80000000u);
}
__device__ __forceinline__ float dec_f32(unsigned u){
    return __uint_as_float((u & 0x80000000u) ? (u ^ 0x80000000u) : ~u);
}
__device__ __forceinline__ unsigned short f2bf(float x){   // RNE
    unsigned u = __float_as_uint(x);
    return (unsigned short)((u + 0x7FFFu + ((u >> 16) & 1u)) >> 16);
}
__device__ __forceinline__ float bf2f(unsigned short h){
    return __uint_as_float(((unsigned)h) << 16);
}
__device__ __forceinline__ void packhl(float4 x, float4 y, bf16x8& H, bf16x8& L){
    float v[8] = {x.x, x.y, x.z, x.w, y.x, y.y, y.z, y.w};
    #pragma unroll
    for (int i = 0; i < 8; ++i){
        unsigned short h = f2bf(v[i]);
        H[i] = (short)h;
        L[i] = (short)f2bf(v[i] - bf2f(h));
    }
}

// ---------------- prep_proj: proj -> B-frag hi/lo layout --------------------
__global__ __launch_bounds__(64) void prep_proj(const float* __restrict__ proj,
                                                char* __restrict__ ws)
{
    const int t = blockIdx.x >> 1, s = blockIdx.x & 1, l = threadIdx.x;
    const int f = t*16 + (l & 15);
    const int k0 = s*32 + (l >> 4)*8;
    bf16x8 H, L;
    #pragma unroll
    for (int i = 0; i < 8; ++i){
        float v = (f < NF) ? proj[f*64 + k0 + i] * NORMALIZER : 0.f;
        unsigned short h = f2bf(v);
        H[i] = (short)h;
        L[i] = (short)f2bf(v - bf2f(h));
    }
    char* base = ws + WS_PROJFRAG + (size_t)((t*2 + s)*2)*1024 + l*16;
    *(bf16x8*)(base)        = H;
    *(bf16x8*)(base + 1024) = L;
}

// ---------------- K2: E=exp(dash-norm), KcumE, CtxE, Sv, gmax ---------------
// grid (split=16, b=64), 256 thr. Block: 128 rows = 2 chunks of 64.
__global__ __launch_bounds__(256, 2) void k2_ctx(const float* __restrict__ kin,
                                                 const float* __restrict__ vin,
                                                 char* __restrict__ ws)
{
    __shared__ __align__(16) char kpb[2][4096];
    __shared__ float nrmL[64];
    __shared__ float redm[4];
    const int tid = threadIdx.x, l = tid & 63, w = tid >> 6;
    const int fq = l & 15, lg = l >> 4;
    const int split = blockIdx.x, b = blockIdx.y;
    const char* pf = ws + WS_PROJFRAG;
    float* kcumE = (float*)(ws + WS_KCUM);
    float* svp   = (float*)(ws + WS_SV);
    float* ctxE  = (float*)(ws + WS_CTX);
    const int e = w*16 + fq;
    const int sw = (fq & 7) << 4;

    f32x4 acc2[17];
    float kc[17];
    #pragma unroll
    for (int t = 0; t < 17; ++t){ acc2[t] = (f32x4){0.f,0.f,0.f,0.f}; kc[t] = 0.f; }
    float sva = 0.f;
    float lmax = -3.0e38f;

    for (int c = 0; c < 2; ++c){
        const long long rowc = (long long)b*SEQ + split*128 + c*64;
        // A-frags: K rows (wave-owned 16 rows)
        const float* rp = kin + (rowc + w*16 + fq)*64 + lg*8;
        float4 a0 = *(const float4*)(rp);
        float4 a1 = *(const float4*)(rp + 4);
        float4 a2 = *(const float4*)(rp + 32);
        float4 a3 = *(const float4*)(rp + 36);
        bf16x8 Ah0, Al0, Ah1, Al1;
        packhl(a0, a1, Ah0, Al0);
        packhl(a2, a3, Ah1, Al1);
        // row norms (0.0625 * sum k^2)
        float np = a0.x*a0.x + a0.y*a0.y + a0.z*a0.z + a0.w*a0.w
                 + a1.x*a1.x + a1.y*a1.y + a1.z*a1.z + a1.w*a1.w
                 + a2.x*a2.x + a2.y*a2.y + a2.z*a2.z + a2.w*a2.w
                 + a3.x*a3.x + a3.y*a3.y + a3.z*a3.z + a3.w*a3.w;
        np += __shfl_xor(np, 16);
        np += __shfl_xor(np, 32);
        if (lg == 0) nrmL[w*16 + fq] = np * 0.0625f;
        // V B-frags for this wave's e-tile + Sv partial
        bf16x8 Vh0, Vl0, Vh1, Vl1;
        {
            float4 x, y;
            float vv[8];
            #pragma unroll
            for (int i = 0; i < 8; ++i){ vv[i] = vin[(rowc + lg*8 + i)*64 + e]; sva += vv[i]; }
            x = make_float4(vv[0],vv[1],vv[2],vv[3]); y = make_float4(vv[4],vv[5],vv[6],vv[7]);
            packhl(x, y, Vh0, Vl0);
            #pragma unroll
            for (int i = 0; i < 8; ++i){ vv[i] = vin[(rowc + 32 + lg*8 + i)*64 + e]; sva += vv[i]; }
            x = make_float4(vv[0],vv[1],vv[2],vv[3]); y = make_float4(vv[4],vv[5],vv[6],vv[7]);
            packhl(x, y, Vh1, Vl1);
        }
        #pragma unroll
        for (int t = 0; t < 17; ++t){
            // GEMM1: dash tile t
            bf16x8 Bh0 = *(const bf16x8*)(pf + (size_t)((t*2+0)*2+0)*1024 + l*16);
            bf16x8 Bl0 = *(const bf16x8*)(pf + (size_t)((t*2+0)*2+1)*1024 + l*16);
            bf16x8 Bh1 = *(const bf16x8*)(pf + (size_t)((t*2+1)*2+0)*1024 + l*16);
            bf16x8 Bl1 = *(const bf16x8*)(pf + (size_t)((t*2+1)*2+1)*1024 + l*16);
            f32x4 d = {0.f, 0.f, 0.f, 0.f};
            d = MFMA(Ah0, Bh0, d); d = MFMA(Ah0, Bl0, d); d = MFMA(Al0, Bh0, d);
            d = MFMA(Ah1, Bh1, d); d = MFMA(Ah1, Bl1, d); d = MFMA(Al1, Bh1, d);
            const bool fv = (t < 16) || (fq < 10);
            if (fv) lmax = fmaxf(lmax, fmaxf(fmaxf(d.x, d.y), fmaxf(d.z, d.w)));
            // E = exp(dash - nrm)  (no gmax, no eps)
            float4 nr4 = *(float4*)&nrmL[w*16 + lg*4];
            float kp0 = fv ? __expf(d.x - nr4.x) : 0.f;
            float kp1 = fv ? __expf(d.y - nr4.y) : 0.f;
            float kp2 = fv ? __expf(d.z - nr4.z) : 0.f;
            float kp3 = fv ? __expf(d.w - nr4.w) : 0.f;
            kc[t] += kp0 + kp1 + kp2 + kp3;
            unsigned short h0 = f2bf(kp0), h1 = f2bf(kp1), h2 = f2bf(kp2), h3 = f2bf(kp3);
            unsigned short o0 = f2bf(kp0 - bf2f(h0)), o1 = f2bf(kp1 - bf2f(h1));
            unsigned short o2 = f2bf(kp2 - bf2f(h2)), o3 = f2bf(kp3 - bf2f(h3));
            char* bufw = kpb[t & 1];
            const int off = w*32 + lg*8;
            *(uint2*)(bufw + fq*256 + ((off      ) ^ sw)) = make_uint2((unsigned)h0 | ((unsigned)h1<<16), (unsigned)h2 | ((unsigned)h3<<16));
            *(uint2*)(bufw + fq*256 + ((off + 128) ^ sw)) = make_uint2((unsigned)o0 | ((unsigned)o1<<16), (unsigned)o2 | ((unsigned)o3<<16));
            // GEMM2: ctx tile t-1 (E^T @ V) from the other buffer
            if (t > 0){
                const char* bufr = kpb[(t-1) & 1];
                bf16x8 Kh0 = *(const bf16x8*)(bufr + fq*256 + ((lg*16      ) ^ sw));
                bf16x8 Kh1 = *(const bf16x8*)(bufr + fq*256 + ((lg*16 +  64) ^ sw));
                bf16x8 Kl0 = *(const bf16x8*)(bufr + fq*256 + ((lg*16 + 128) ^ sw));
                bf16x8 Kl1 = *(const bf16x8*)(bufr + fq*256 + ((lg*16 + 192) ^ sw));
                f32x4 a = acc2[t-1];
                a = MFMA(Kh0, Vh0, a); a = MFMA(Kh0, Vl0, a); a = MFMA(Kl0, Vh0, a);
                a = MFMA(Kh1, Vh1, a); a = MFMA(Kh1, Vl1, a); a = MFMA(Kl1, Vh1, a);
                acc2[t-1] = a;
            }
            __syncthreads();
        }
        {   // epilogue: GEMM2 tile 16 (buffer 0)
            const char* bufr = kpb[0];
            bf16x8 Kh0 = *(const bf16x8*)(bufr + fq*256 + ((lg*16      ) ^ sw));
            bf16x8 Kh1 = *(const bf16x8*)(bufr + fq*256 + ((lg*16 +  64) ^ sw));
            bf16x8 Kl0 = *(const bf16x8*)(bufr + fq*256 + ((lg*16 + 128) ^ sw));
            bf16x8 Kl1 = *(const bf16x8*)(bufr + fq*256 + ((lg*16 + 192) ^ sw));
            f32x4 a = acc2[16];
            a = MFMA(Kh0, Vh0, a); a = MFMA(Kh0, Vl0, a); a = MFMA(Kl0, Vh0, a);
            a = MFMA(Kh1, Vh1, a); a = MFMA(Kh1, Vl1, a); a = MFMA(Kl1, Vh1, a);
            acc2[16] = a;
        }
        __syncthreads();
    }
    // Sv flush (covers this block's 128 rows)
    sva += __shfl_xor(sva, 16);
    sva += __shfl_xor(sva, 32);
    if (lg == 0) atomicAdd(&svp[b*64 + e], sva);
    // flush kcumE + ctxE
    #pragma unroll
    for (int t = 0; t < 17; ++t){
        float s = kc[t];
        s += __shfl_xor(s, 16);
        s += __shfl_xor(s, 32);
        const int f = t*16 + fq;
        if (lg == 0 && f < NF) atomicAdd(&kcumE[b*NF2 + f], s);
        const int fr = t*16 + lg*4;
        if (fr + 0 < NF) atomicAdd(&ctxE[((size_t)b*NF2 + fr + 0)*64 + e], acc2[t].x);
        if (fr + 1 < NF) atomicAdd(&ctxE[((size_t)b*NF2 + fr + 1)*64 + e], acc2[t].y);
        if (fr + 2 < NF) atomicAdd(&ctxE[((size_t)b*NF2 + fr + 2)*64 + e], acc2[t].z);
        if (fr + 3 < NF) atomicAdd(&ctxE[((size_t)b*NF2 + fr + 3)*64 + e], acc2[t].w);
    }
    // gmax
    #pragma unroll
    for (int off = 1; off < 64; off <<= 1)
        lmax = fmaxf(lmax, __shfl_xor(lmax, off));
    if (l == 0) redm[w] = lmax;
    __syncthreads();
    if (tid == 0)
        atomicMax((unsigned*)ws,
                  enc_f32(fmaxf(fmaxf(redm[0], redm[1]), fmaxf(redm[2], redm[3]))));
}

// ---------------- prep_ctx: compose + f16 hi/lo frag pack -------------------
// ctx = e^{-gmax}*CtxE + eps*Sv ; per (b, nt, ks): e = nt*16+(l&15), f = ks*32+(l>>4)*8+i
__global__ __launch_bounds__(64) void prep_ctx(char* __restrict__ ws)
{
    const int b = blockIdx.x / 36, r = blockIdx.x % 36, nt = r / 9, ks = r % 9;
    const int l = threadIdx.x;
    const float* ctxE = (const float*)(ws + WS_CTX) + (size_t)b*NF2*64;
    const float* svp  = (const float*)(ws + WS_SV) + b*64;
    const float gmax = dec_f32(*(const unsigned*)ws);
    const float sc = __expf(-gmax);
    const int e = nt*16 + (l & 15);
    const int f0 = ks*32 + (l >> 4)*8;
    const float sve = svp[e] * EPS_F;
    f16x8 H, L;
    #pragma unroll
    for (int i = 0; i < 8; ++i){
        const int f = f0 + i;
        float v = (f < NF) ? sc*ctxE[(size_t)f*64 + e] + sve : 0.f;
        _Float16 h = (_Float16)v;
        H[i] = h;
        L[i] = (_Float16)(v - (float)h);
    }
    char* base = ws + WS_CTXFRAG + (size_t)b*73728 + nt*18432 + ks*2048 + l*16;
    *(f16x8*)(base)        = H;
    *(f16x8*)(base + 1024) = L;
}

// ---------------- K3: qp, D, out (dash bf16-MFMA, out f16-MFMA) -------------
__global__ __launch_bounds__(256, 2) void k3_out(const float* __restrict__ qin,
                                                 const char* __restrict__ ws,
                                                 float* __restrict__ out)
{
    __shared__ __align__(16) char qpb[64*592];   // [64 rows][296 f16], pad stride
    __shared__ float nrmL[64];
    __shared__ float kcumL[NF2];
    const int tid = threadIdx.x, l = tid & 63, w = tid >> 6;
    const int fq = l & 15, lg = l >> 4;
    const int b = blockIdx.x >> 5;
    const long long rowb = (long long)blockIdx.x*64;
    const char* pf = ws + WS_PROJFRAG;
    const char* cf = ws + WS_CTXFRAG + (size_t)b*73728;
    const float* kcumE = (const float*)(ws + WS_KCUM) + (size_t)b*NF2;
    const float gmax = dec_f32(*(const unsigned*)ws);
    const float sc = __expf(-gmax);

    for (int i = tid; i < NF2; i += 256)
        kcumL[i] = (i < NF) ? sc*kcumE[i] + EPS_F*2048.0f : 0.f;
    for (int i = tid; i < 64*16; i += 256){           // zero pad f in [272,288)
        int rr = i >> 4;
        *(short*)(qpb + (size_t)rr*592 + (272 + (i & 15))*2) = 0;
    }
    // A-frags: Q rows + norms
    const float* rp = qin + (rowb + w*16 + fq)*64 + lg*8;
    float4 a0 = *(const float4*)(rp);
    float4 a1 = *(const float4*)(rp + 4);
    float4 a2 = *(const float4*)(rp + 32);
    float4 a3 = *(const float4*)(rp + 36);
    bf16x8 Ah0, Al0, Ah1, Al1;
    packhl(a0, a1, Ah0, Al0);
    packhl(a2, a3, Ah1, Al1);
    float np = a0.x*a0.x + a0.y*a0.y + a0.z*a0.z + a0.w*a0.w
             + a1.x*a1.x + a1.y*a1.y + a1.z*a1.z + a1.w*a1.w
             + a2.x*a2.x + a2.y*a2.y + a2.z*a2.z + a2.w*a2.w
             + a3.x*a3.x + a3.y*a3.y + a3.z*a3.z + a3.w*a3.w;
    np += __shfl_xor(np, 16);
    np += __shfl_xor(np, 32);
    if (lg == 0) nrmL[w*16 + fq] = np * 0.0625f;
    __syncthreads();
    // dash for all 17 f-tiles (registers)
    f32x4 p[17];
    #pragma unroll
    for (int t = 0; t < 17; ++t){
        bf16x8 Bh0 = *(const bf16x8*)(pf + (size_t)((t*2+0)*2+0)*1024 + l*16);
        bf16x8 Bl0 = *(const bf16x8*)(pf + (size_t)((t*2+0)*2+1)*1024 + l*16);
        bf16x8 Bh1 = *(const bf16x8*)(pf + (size_t)((t*2+1)*2+0)*1024 + l*16);
        bf16x8 Bl1 = *(const bf16x8*)(pf + (size_t)((t*2+1)*2+1)*1024 + l*16);
        f32x4 d = {0.f, 0.f, 0.f, 0.f};
        d = MFMA(Ah0, Bh0, d); d = MFMA(Ah0, Bl0, d); d = MFMA(Al0, Bh0, d);
        d = MFMA(Ah1, Bh1, d); d = MFMA(Ah1, Bl1, d); d = MFMA(Al1, Bh1, d);
        p[t] = d;
    }
    // per-row max (over real features)
    float mx0 = -3.0e38f, mx1 = -3.0e38f, mx2 = -3.0e38f, mx3 = -3.0e38f;
    #pragma unroll
    for (int t = 0; t < 17; ++t){
        if (t < 16 || fq < 10){
            mx0 = fmaxf(mx0, p[t].x); mx1 = fmaxf(mx1, p[t].y);
            mx2 = fmaxf(mx2, p[t].z); mx3 = fmaxf(mx3, p[t].w);
        }
    }
    #pragma unroll
    for (int off = 1; off < 16; off <<= 1){
        mx0 = fmaxf(mx0, __shfl_xor(mx0, off));
        mx1 = fmaxf(mx1, __shfl_xor(mx1, off));
        mx2 = fmaxf(mx2, __shfl_xor(mx2, off));
        mx3 = fmaxf(mx3, __shfl_xor(mx3, off));
    }
    // qp = exp(dash - nrm - rowmax) + eps ; D = qp . kcum
    float4 nr4 = *(float4*)&nrmL[w*16 + lg*4];
    float d0 = 0.f, d1 = 0.f, d2 = 0.f, d3 = 0.f;
    #pragma unroll
    for (int t = 0; t < 17; ++t){
        const bool fv = (t < 16) || (fq < 10);
        float q0 = fv ? (__expf(p[t].x - nr4.x - mx0) + EPS_F) : 0.f;
        float q1 = fv ? (__expf(p[t].y - nr4.y - mx1) + EPS_F) : 0.f;
        float q2 = fv ? (__expf(p[t].z - nr4.z - mx2) + EPS_F) : 0.f;
        float q3 = fv ? (__expf(p[t].w - nr4.w - mx3) + EPS_F) : 0.f;
        const float kcv = kcumL[t*16 + fq];
        d0 += q0*kcv; d1 += q1*kcv; d2 += q2*kcv; d3 += q3*kcv;
        p[t].x = q0; p[t].y = q1; p[t].z = q2; p[t].w = q3;
    }
    #pragma unroll
    for (int off = 1; off < 16; off <<= 1){
        d0 += __shfl_xor(d0, off); d1 += __shfl_xor(d1, off);
        d2 += __shfl_xor(d2, off); d3 += __shfl_xor(d3, off);
    }
    const float iv0 = 1.f/d0, iv1 = 1.f/d1, iv2 = 1.f/d2, iv3 = 1.f/d3;
    // write qp as f16 (single plane)
    #pragma unroll
    for (int t = 0; t < 17; ++t){
        const int fb = (t*16 + fq)*2;
        *(short*)(qpb + (size_t)(w*16 + lg*4 + 0)*592 + fb) = __builtin_bit_cast(short, (_Float16)p[t].x);
        *(short*)(qpb + (size_t)(w*16 + lg*4 + 1)*592 + fb) = __builtin_bit_cast(short, (_Float16)p[t].y);
        *(short*)(qpb + (size_t)(w*16 + lg*4 + 2)*592 + fb) = __builtin_bit_cast(short, (_Float16)p[t].z);
        *(short*)(qpb + (size_t)(w*16 + lg*4 + 3)*592 + fb) = __builtin_bit_cast(short, (_Float16)p[t].w);
    }
    __syncthreads();
    f32x4 o[4];
    #pragma unroll
    for (int nt = 0; nt < 4; ++nt) o[nt] = (f32x4){0.f,0.f,0.f,0.f};
    #pragma unroll
    for (int ks = 0; ks < 9; ++ks){
        f16x8 Aq = __builtin_bit_cast(f16x8,
                   *(const bf16x8*)(qpb + (size_t)(w*16 + fq)*592 + ks*64 + lg*16));
        #pragma unroll
        for (int nt = 0; nt < 4; ++nt){
            f16x8 Bh = __builtin_bit_cast(f16x8, *(const bf16x8*)(cf + nt*18432 + ks*2048 + l*16));
            f16x8 Bl = __builtin_bit_cast(f16x8, *(const bf16x8*)(cf + nt*18432 + ks*2048 + 1024 + l*16));
            o[nt] = MFMAH(Aq, Bh, o[nt]);
            o[nt] = MFMAH(Aq, Bl, o[nt]);
        }
    }
    // store out = o * Dinv
    #pragma unroll
    for (int nt = 0; nt < 4; ++nt){
        const size_t rb = (size_t)(rowb + w*16 + lg*4);
        out[(rb + 0)*64 + nt*16 + fq] = o[nt].x * iv0;
        out[(rb + 1)*64 + nt*16 + fq] = o[nt].y * iv1;
        out[(rb + 2)*64 + nt*16 + fq] = o[nt].z * iv2;
        out[(rb + 3)*64 + nt*16 + fq] = o[nt].w * iv3;
    }
}

extern "C" void kernel_launch(void* const* d_in, const int* in_sizes, int n_in,
                              void* d_out, int out_size, void* d_ws, size_t ws_size,
                              hipStream_t stream)
{
    const float* q    = (const float*)d_in[0];
    const float* k    = (const float*)d_in[1];
    const float* v    = (const float*)d_in[2];
    const float* proj = (const float*)d_in[3];
    float* out = (float*)d_out;
    char* ws = (char*)d_ws;

    hipMemsetAsync(ws, 0, WS_ZERO_BYTES, stream);
    prep_proj<<<34, 64, 0, stream>>>(proj, ws);
    k2_ctx<<<dim3(16, 64), 256, 0, stream>>>(k, v, ws);
    prep_ctx<<<2304, 64, 0, stream>>>(ws);
    k3_out<<<2048, 256, 0, stream>>>(q, ws, out);
}

// Round 5
// 272.741 us; speedup vs baseline: 6.0901x; 1.2980x over previous
//
#include <hip/hip_runtime.h>
#include <math.h>

// Performer attention (FAVOR+), B=64, N=2048, d=64, m=266, fp32 in/out.
// Round 5 (= round 4 + compile fix): barrier-free k2. Key identity: the
// mfma_16x16x32 D-layout (lane fq,lg reg r -> [row=lg*4+r][col=fq]) IS the
// A-frag layout of mfma_16x16x16_bf16 (lane holds A[row=l&15][k=(l>>4)*4+i]),
// so kp goes GEMM1 -> exp -> GEMM2 entirely in registers. f-tiles split
// across the 4 waves (wave w: tiles {w,4+w,8+w,12+w} + e-slice nt==w of
// tile 16); waves fully independent -> zero LDS, zero __syncthreads in k2.
// ratio = m^-0.5 cancels exactly in out -> omitted.
// kp = e^{-gmax}*exp(dash-norm)+eps identity removes the k1 max pre-pass.

#define SEQ   2048
#define NF    266
#define NF2   288
#define NORMALIZER 0.35355339059327379f   // 64^-0.25
#define EPS_F 1e-4f

// ws layout (bytes)
#define WS_PROJFRAG 256                    // 17*2*2*1024 = 69632 -> 69888
#define WS_KCUM     69888                  // 64*288*4    = 73728 -> 143616
#define WS_SV       143616                 // 64*64*4     = 16384 -> 160000
#define WS_CTX      160000                 // 64*288*64*4 = 4718592 -> 4878592
#define WS_CTXFRAG  4878592                // 64*73728    = 4718592 -> 9597184
#define WS_ZERO_BYTES 4878592

typedef __attribute__((ext_vector_type(8))) short bf16x8;
typedef __attribute__((ext_vector_type(4))) short bf16x4;
typedef __attribute__((ext_vector_type(8))) _Float16 f16x8;
typedef __attribute__((ext_vector_type(4))) float f32x4;
#define MFMA(A,B,C)   __builtin_amdgcn_mfma_f32_16x16x32_bf16(A,B,C,0,0,0)
#define MFMAH(A,B,C)  __builtin_amdgcn_mfma_f32_16x16x32_f16(A,B,C,0,0,0)
#define MFMA16(A,B,C) __builtin_amdgcn_mfma_f32_16x16x16bf16_1k(A,B,C,0,0,0)

__device__ __forceinline__ unsigned enc_f32(float f){
    unsigned u = __float_as_uint(f);
    return (u & 0x80000000u) ? ~u : (u | 0x80000000u);
}
__device__ __forceinline__ float dec_f32(unsigned u){
    return __uint_as_float((u & 0x80000000u) ? (u ^ 0x80000000u) : ~u);
}
__device__ __forceinline__ unsigned short f2bf(float x){   // RNE
    unsigned u = __float_as_uint(x);
    return (unsigned short)((u + 0x7FFFu + ((u >> 16) & 1u)) >> 16);
}
__device__ __forceinline__ float bf2f(unsigned short h){
    return __uint_as_float(((unsigned)h) << 16);
}
__device__ __forceinline__ void packhl(float4 x, float4 y, bf16x8& H, bf16x8& L){
    float v[8] = {x.x, x.y, x.z, x.w, y.x, y.y, y.z, y.w};
    #pragma unroll
    for (int i = 0; i < 8; ++i){
        unsigned short h = f2bf(v[i]);
        H[i] = (short)h;
        L[i] = (short)f2bf(v[i] - bf2f(h));
    }
}
// trunc-split: hi = trunc-bf16(x), lo = trunc-bf16(x - hi). Error <= 2^-16 rel
// when used as Ah*Bh + Ah*Bl + Al*Bh.
__device__ __forceinline__ void split8(float4 x, float4 y, bf16x8& H, bf16x8& L){
    float v[8] = {x.x, x.y, x.z, x.w, y.x, y.y, y.z, y.w};
    #pragma unroll
    for (int i = 0; i < 8; ++i){
        unsigned u  = __float_as_uint(v[i]);
        unsigned uh = u & 0xFFFF0000u;
        H[i] = (short)(uh >> 16);
        L[i] = (short)(__float_as_uint(v[i] - __uint_as_float(uh)) >> 16);
    }
}
__device__ __forceinline__ void split4(float v0, float v1, float v2, float v3,
                                       bf16x4& H, bf16x4& L){
    float v[4] = {v0, v1, v2, v3};
    #pragma unroll
    for (int i = 0; i < 4; ++i){
        unsigned u  = __float_as_uint(v[i]);
        unsigned uh = u & 0xFFFF0000u;
        H[i] = (short)(uh >> 16);
        L[i] = (short)(__float_as_uint(v[i] - __uint_as_float(uh)) >> 16);
    }
}

// ---------------- prep_proj: proj -> B-frag hi/lo layout --------------------
__global__ __launch_bounds__(64) void prep_proj(const float* __restrict__ proj,
                                                char* __restrict__ ws)
{
    const int t = blockIdx.x >> 1, s = blockIdx.x & 1, l = threadIdx.x;
    const int f = t*16 + (l & 15);
    const int k0 = s*32 + (l >> 4)*8;
    bf16x8 H, L;
    #pragma unroll
    for (int i = 0; i < 8; ++i){
        float v = (f < NF) ? proj[f*64 + k0 + i] * NORMALIZER : 0.f;
        unsigned short h = f2bf(v);
        H[i] = (short)h;
        L[i] = (short)f2bf(v - bf2f(h));
    }
    char* base = ws + WS_PROJFRAG + (size_t)((t*2 + s)*2)*1024 + l*16;
    *(bf16x8*)(base)        = H;
    *(bf16x8*)(base + 1024) = L;
}

// ---------------- K2: barrier-free. E=exp(dash-norm), KcumE, CtxE, Sv, gmax -
// grid (split=8, b=64), 256 thr. Wave w owns f-tiles {w,4+w,8+w,12+w} fully
// and e-slice nt==w of tile 16. 256 rows/block in 16 steps of 16 rows; all
// waves process the same rows (K/V loads hit L1).
__global__ __launch_bounds__(256, 2) void k2_ctx(const float* __restrict__ kin,
                                                 const float* __restrict__ vin,
                                                 char* __restrict__ ws)
{
    const int tid = threadIdx.x, l = tid & 63, w = tid >> 6;
    const int fq = l & 15, lg = l >> 4;
    const int split = blockIdx.x, b = blockIdx.y;
    const char* pf = ws + WS_PROJFRAG;
    float* kcumE = (float*)(ws + WS_KCUM);
    float* svp   = (float*)(ws + WS_SV);
    float* ctxE  = (float*)(ws + WS_CTX);

    // hoisted proj B-frags for this wave's 4 main tiles
    bf16x8 Bh0[4], Bl0[4], Bh1[4], Bl1[4];
    #pragma unroll
    for (int j = 0; j < 4; ++j){
        const int t = w + 4*j;
        Bh0[j] = *(const bf16x8*)(pf + (size_t)((t*2+0)*2+0)*1024 + l*16);
        Bl0[j] = *(const bf16x8*)(pf + (size_t)((t*2+0)*2+1)*1024 + l*16);
        Bh1[j] = *(const bf16x8*)(pf + (size_t)((t*2+1)*2+0)*1024 + l*16);
        Bl1[j] = *(const bf16x8*)(pf + (size_t)((t*2+1)*2+1)*1024 + l*16);
    }

    f32x4 acc[4][4];
    f32x4 acc16 = (f32x4){0.f,0.f,0.f,0.f};
    float kc[4] = {0.f,0.f,0.f,0.f};
    float kc16 = 0.f;
    float svacc[4] = {0.f,0.f,0.f,0.f};
    float lmax = -3.0e38f;
    #pragma unroll
    for (int j = 0; j < 4; ++j)
        #pragma unroll
        for (int nt = 0; nt < 4; ++nt)
            acc[j][nt] = (f32x4){0.f,0.f,0.f,0.f};

    const size_t rowblk = (size_t)b*SEQ + (size_t)split*256;
    for (int s = 0; s < 16; ++s){
        const size_t row0 = rowblk + s*16;
        // ---- K A-frags (16 rows; lane: row fq, cols lg*8.. two k-steps)
        const float* rp = kin + (row0 + fq)*64 + lg*8;
        float4 a0 = *(const float4*)(rp);
        float4 a1 = *(const float4*)(rp + 4);
        float4 a2 = *(const float4*)(rp + 32);
        float4 a3 = *(const float4*)(rp + 36);
        bf16x8 Ah0, Al0, Ah1, Al1;
        split8(a0, a1, Ah0, Al0);
        split8(a2, a3, Ah1, Al1);
        // ---- row norms: np = 0.0625 * |k_row fq|^2, broadcast rows lg*4+r
        float np = a0.x*a0.x + a0.y*a0.y + a0.z*a0.z + a0.w*a0.w
                 + a1.x*a1.x + a1.y*a1.y + a1.z*a1.z + a1.w*a1.w
                 + a2.x*a2.x + a2.y*a2.y + a2.z*a2.z + a2.w*a2.w
                 + a3.x*a3.x + a3.y*a3.y + a3.z*a3.z + a3.w*a3.w;
        np += __shfl_xor(np, 16);
        np += __shfl_xor(np, 32);
        np *= 0.0625f;
        const float nr0 = __shfl(np, lg*4 + 0);
        const float nr1 = __shfl(np, lg*4 + 1);
        const float nr2 = __shfl(np, lg*4 + 2);
        const float nr3 = __shfl(np, lg*4 + 3);
        // ---- V B-frags for 16x16x16 (lane: k=lg*4+i rows, col=nt*16+fq) + Sv
        const float* vp = vin + (row0 + lg*4)*64 + fq;
        bf16x4 Vh[4], Vl[4];
        #pragma unroll
        for (int nt = 0; nt < 4; ++nt){
            float v0 = vp[nt*16      ];
            float v1 = vp[nt*16 +  64];
            float v2 = vp[nt*16 + 128];
            float v3 = vp[nt*16 + 192];
            svacc[nt] += v0 + v1 + v2 + v3;
            split4(v0, v1, v2, v3, Vh[nt], Vl[nt]);
        }
        // ---- main tiles: dash -> exp -> (registers!) -> ctx GEMM2
        #pragma unroll
        for (int j = 0; j < 4; ++j){
            f32x4 d = {0.f,0.f,0.f,0.f};
            d = MFMA(Ah0, Bh0[j], d); d = MFMA(Ah0, Bl0[j], d); d = MFMA(Al0, Bh0[j], d);
            d = MFMA(Ah1, Bh1[j], d); d = MFMA(Ah1, Bl1[j], d); d = MFMA(Al1, Bh1[j], d);
            lmax = fmaxf(lmax, fmaxf(fmaxf(d.x, d.y), fmaxf(d.z, d.w)));
            float kp0 = __expf(d.x - nr0);
            float kp1 = __expf(d.y - nr1);
            float kp2 = __expf(d.z - nr2);
            float kp3 = __expf(d.w - nr3);
            kc[j] += kp0 + kp1 + kp2 + kp3;
            bf16x4 Kh, Kl;
            split4(kp0, kp1, kp2, kp3, Kh, Kl);   // D-layout == A-frag layout
            #pragma unroll
            for (int nt = 0; nt < 4; ++nt){
                f32x4 a = acc[j][nt];
                a = MFMA16(Kh, Vh[nt], a);
                a = MFMA16(Kh, Vl[nt], a);
                a = MFMA16(Kl, Vh[nt], a);
                acc[j][nt] = a;
            }
        }
        // ---- tile 16 (f 256..271, valid f<266): computed by all waves,
        //      each wave accumulates only its e-slice nt==w
        {
            bf16x8 Th0 = *(const bf16x8*)(pf + (size_t)((16*2+0)*2+0)*1024 + l*16);
            bf16x8 Tl0 = *(const bf16x8*)(pf + (size_t)((16*2+0)*2+1)*1024 + l*16);
            bf16x8 Th1 = *(const bf16x8*)(pf + (size_t)((16*2+1)*2+0)*1024 + l*16);
            bf16x8 Tl1 = *(const bf16x8*)(pf + (size_t)((16*2+1)*2+1)*1024 + l*16);
            f32x4 d = {0.f,0.f,0.f,0.f};
            d = MFMA(Ah0, Th0, d); d = MFMA(Ah0, Tl0, d); d = MFMA(Al0, Th0, d);
            d = MFMA(Ah1, Th1, d); d = MFMA(Ah1, Tl1, d); d = MFMA(Al1, Th1, d);
            const bool fv = (fq < 10);
            if (fv) lmax = fmaxf(lmax, fmaxf(fmaxf(d.x, d.y), fmaxf(d.z, d.w)));
            float kp0 = fv ? __expf(d.x - nr0) : 0.f;
            float kp1 = fv ? __expf(d.y - nr1) : 0.f;
            float kp2 = fv ? __expf(d.z - nr2) : 0.f;
            float kp3 = fv ? __expf(d.w - nr3) : 0.f;
            kc16 += kp0 + kp1 + kp2 + kp3;
            bf16x4 Kh, Kl;
            split4(kp0, kp1, kp2, kp3, Kh, Kl);
            acc16 = MFMA16(Kh, Vh[w], acc16);
            acc16 = MFMA16(Kh, Vl[w], acc16);
            acc16 = MFMA16(Kl, Vh[w], acc16);
        }
    }

    // ---------------- flush (atomics; no block coordination needed) ---------
    // gmax (per wave)
    #pragma unroll
    for (int off = 1; off < 64; off <<= 1)
        lmax = fmaxf(lmax, __shfl_xor(lmax, off));
    if (l == 0) atomicMax((unsigned*)ws, enc_f32(lmax));
    // Sv (rows shared by all 4 waves -> only wave 0 flushes)
    if (w == 0){
        #pragma unroll
        for (int nt = 0; nt < 4; ++nt){
            float sv = svacc[nt];
            sv += __shfl_xor(sv, 16);
            sv += __shfl_xor(sv, 32);
            if (lg == 0) atomicAdd(&svp[b*64 + nt*16 + fq], sv);
        }
    }
    // kcumE: main tiles (unique per wave)
    #pragma unroll
    for (int j = 0; j < 4; ++j){
        float sK = kc[j];
        sK += __shfl_xor(sK, 16);
        sK += __shfl_xor(sK, 32);
        if (lg == 0) atomicAdd(&kcumE[b*NF2 + (w + 4*j)*16 + fq], sK);
    }
    // kcumE tile 16 (identical in all waves -> wave 0, fq<10)
    if (w == 0){
        float sK = kc16;
        sK += __shfl_xor(sK, 16);
        sK += __shfl_xor(sK, 32);
        if (lg == 0 && fq < 10) atomicAdd(&kcumE[b*NF2 + 256 + fq], sK);
    }
    // ctxE: acc[j][nt] reg r = ctx[f=(w+4j)*16+lg*4+r][e=nt*16+fq]
    #pragma unroll
    for (int j = 0; j < 4; ++j){
        const int fr = (w + 4*j)*16 + lg*4;
        #pragma unroll
        for (int nt = 0; nt < 4; ++nt){
            float* cb = &ctxE[((size_t)b*NF2 + fr)*64 + nt*16 + fq];
            atomicAdd(cb +   0, acc[j][nt].x);
            atomicAdd(cb +  64, acc[j][nt].y);
            atomicAdd(cb + 128, acc[j][nt].z);
            atomicAdd(cb + 192, acc[j][nt].w);
        }
    }
    // ctxE tile 16: e-slice nt==w, rows 256+lg*4+r (valid < 266)
    {
        const int fr = 256 + lg*4;
        float* cb = &ctxE[((size_t)b*NF2 + fr)*64 + w*16 + fq];
        if (fr + 0 < NF) atomicAdd(cb +   0, acc16.x);
        if (fr + 1 < NF) atomicAdd(cb +  64, acc16.y);
        if (fr + 2 < NF) atomicAdd(cb + 128, acc16.z);
        if (fr + 3 < NF) atomicAdd(cb + 192, acc16.w);
    }
}

// ---------------- prep_ctx: compose + f16 hi/lo frag pack -------------------
// ctx = e^{-gmax}*CtxE + eps*Sv ; per (b, nt, ks): e = nt*16+(l&15), f = ks*32+(l>>4)*8+i
__global__ __launch_bounds__(64) void prep_ctx(char* __restrict__ ws)
{
    const int b = blockIdx.x / 36, r = blockIdx.x % 36, nt = r / 9, ks = r % 9;
    const int l = threadIdx.x;
    const float* ctxE = (const float*)(ws + WS_CTX) + (size_t)b*NF2*64;
    const float* svp  = (const float*)(ws + WS_SV) + b*64;
    const float gmax = dec_f32(*(const unsigned*)ws);
    const float sc = __expf(-gmax);
    const int e = nt*16 + (l & 15);
    const int f0 = ks*32 + (l >> 4)*8;
    const float sve = svp[e] * EPS_F;
    f16x8 H, L;
    #pragma unroll
    for (int i = 0; i < 8; ++i){
        const int f = f0 + i;
        float v = (f < NF) ? sc*ctxE[(size_t)f*64 + e] + sve : 0.f;
        _Float16 h = (_Float16)v;
        H[i] = h;
        L[i] = (_Float16)(v - (float)h);
    }
    char* base = ws + WS_CTXFRAG + (size_t)b*73728 + nt*18432 + ks*2048 + l*16;
    *(f16x8*)(base)        = H;
    *(f16x8*)(base + 1024) = L;
}

// ---------------- K3: qp, D, out (dash bf16-MFMA, out f16-MFMA) -------------
__global__ __launch_bounds__(256, 2) void k3_out(const float* __restrict__ qin,
                                                 const char* __restrict__ ws,
                                                 float* __restrict__ out)
{
    __shared__ __align__(16) char qpb[64*592];   // [64 rows][296 f16], pad stride
    __shared__ float nrmL[64];
    __shared__ float kcumL[NF2];
    const int tid = threadIdx.x, l = tid & 63, w = tid >> 6;
    const int fq = l & 15, lg = l >> 4;
    const int b = blockIdx.x >> 5;
    const long long rowb = (long long)blockIdx.x*64;
    const char* pf = ws + WS_PROJFRAG;
    const char* cf = ws + WS_CTXFRAG + (size_t)b*73728;
    const float* kcumE = (const float*)(ws + WS_KCUM) + (size_t)b*NF2;
    const float gmax = dec_f32(*(const unsigned*)ws);
    const float sc = __expf(-gmax);

    for (int i = tid; i < NF2; i += 256)
        kcumL[i] = (i < NF) ? sc*kcumE[i] + EPS_F*2048.0f : 0.f;
    for (int i = tid; i < 64*16; i += 256){           // zero pad f in [272,288)
        int rr = i >> 4;
        *(short*)(qpb + (size_t)rr*592 + (272 + (i & 15))*2) = 0;
    }
    // A-frags: Q rows + norms
    const float* rp = qin + (rowb + w*16 + fq)*64 + lg*8;
    float4 a0 = *(const float4*)(rp);
    float4 a1 = *(const float4*)(rp + 4);
    float4 a2 = *(const float4*)(rp + 32);
    float4 a3 = *(const float4*)(rp + 36);
    bf16x8 Ah0, Al0, Ah1, Al1;
    packhl(a0, a1, Ah0, Al0);
    packhl(a2, a3, Ah1, Al1);
    float np = a0.x*a0.x + a0.y*a0.y + a0.z*a0.z + a0.w*a0.w
             + a1.x*a1.x + a1.y*a1.y + a1.z*a1.z + a1.w*a1.w
             + a2.x*a2.x + a2.y*a2.y + a2.z*a2.z + a2.w*a2.w
             + a3.x*a3.x + a3.y*a3.y + a3.z*a3.z + a3.w*a3.w;
    np += __shfl_xor(np, 16);
    np += __shfl_xor(np, 32);
    if (lg == 0) nrmL[w*16 + fq] = np * 0.0625f;
    __syncthreads();
    // dash for all 17 f-tiles (registers)
    f32x4 p[17];
    #pragma unroll
    for (int t = 0; t < 17; ++t){
        bf16x8 Bh0 = *(const bf16x8*)(pf + (size_t)((t*2+0)*2+0)*1024 + l*16);
        bf16x8 Bl0 = *(const bf16x8*)(pf + (size_t)((t*2+0)*2+1)*1024 + l*16);
        bf16x8 Bh1 = *(const bf16x8*)(pf + (size_t)((t*2+1)*2+0)*1024 + l*16);
        bf16x8 Bl1 = *(const bf16x8*)(pf + (size_t)((t*2+1)*2+1)*1024 + l*16);
        f32x4 d = {0.f, 0.f, 0.f, 0.f};
        d = MFMA(Ah0, Bh0, d); d = MFMA(Ah0, Bl0, d); d = MFMA(Al0, Bh0, d);
        d = MFMA(Ah1, Bh1, d); d = MFMA(Ah1, Bl1, d); d = MFMA(Al1, Bh1, d);
        p[t] = d;
    }
    // per-row max (over real features)
    float mx0 = -3.0e38f, mx1 = -3.0e38f, mx2 = -3.0e38f, mx3 = -3.0e38f;
    #pragma unroll
    for (int t = 0; t < 17; ++t){
        if (t < 16 || fq < 10){
            mx0 = fmaxf(mx0, p[t].x); mx1 = fmaxf(mx1, p[t].y);
            mx2 = fmaxf(mx2, p[t].z); mx3 = fmaxf(mx3, p[t].w);
        }
    }
    #pragma unroll
    for (int off = 1; off < 16; off <<= 1){
        mx0 = fmaxf(mx0, __shfl_xor(mx0, off));
        mx1 = fmaxf(mx1, __shfl_xor(mx1, off));
        mx2 = fmaxf(mx2, __shfl_xor(mx2, off));
        mx3 = fmaxf(mx3, __shfl_xor(mx3, off));
    }
    // qp = exp(dash - nrm - rowmax) + eps ; D = qp . kcum
    float4 nr4 = *(float4*)&nrmL[w*16 + lg*4];
    float d0 = 0.f, d1 = 0.f, d2 = 0.f, d3 = 0.f;
    #pragma unroll
    for (int t = 0; t < 17; ++t){
        const bool fv = (t < 16) || (fq < 10);
        float q0 = fv ? (__expf(p[t].x - nr4.x - mx0) + EPS_F) : 0.f;
        float q1 = fv ? (__expf(p[t].y - nr4.y - mx1) + EPS_F) : 0.f;
        float q2 = fv ? (__expf(p[t].z - nr4.z - mx2) + EPS_F) : 0.f;
        float q3 = fv ? (__expf(p[t].w - nr4.w - mx3) + EPS_F) : 0.f;
        const float kcv = kcumL[t*16 + fq];
        d0 += q0*kcv; d1 += q1*kcv; d2 += q2*kcv; d3 += q3*kcv;
        p[t].x = q0; p[t].y = q1; p[t].z = q2; p[t].w = q3;
    }
    #pragma unroll
    for (int off = 1; off < 16; off <<= 1){
        d0 += __shfl_xor(d0, off); d1 += __shfl_xor(d1, off);
        d2 += __shfl_xor(d2, off); d3 += __shfl_xor(d3, off);
    }
    const float iv0 = 1.f/d0, iv1 = 1.f/d1, iv2 = 1.f/d2, iv3 = 1.f/d3;
    // write qp as f16 (single plane)
    #pragma unroll
    for (int t = 0; t < 17; ++t){
        const int fb = (t*16 + fq)*2;
        *(short*)(qpb + (size_t)(w*16 + lg*4 + 0)*592 + fb) = __builtin_bit_cast(short, (_Float16)p[t].x);
        *(short*)(qpb + (size_t)(w*16 + lg*4 + 1)*592 + fb) = __builtin_bit_cast(short, (_Float16)p[t].y);
        *(short*)(qpb + (size_t)(w*16 + lg*4 + 2)*592 + fb) = __builtin_bit_cast(short, (_Float16)p[t].z);
        *(short*)(qpb + (size_t)(w*16 + lg*4 + 3)*592 + fb) = __builtin_bit_cast(short, (_Float16)p[t].w);
    }
    __syncthreads();
    f32x4 o[4];
    #pragma unroll
    for (int nt = 0; nt < 4; ++nt) o[nt] = (f32x4){0.f,0.f,0.f,0.f};
    #pragma unroll
    for (int ks = 0; ks < 9; ++ks){
        f16x8 Aq = __builtin_bit_cast(f16x8,
                   *(const bf16x8*)(qpb + (size_t)(w*16 + fq)*592 + ks*64 + lg*16));
        #pragma unroll
        for (int nt = 0; nt < 4; ++nt){
            f16x8 Bh = __builtin_bit_cast(f16x8, *(const bf16x8*)(cf + nt*18432 + ks*2048 + l*16));
            f16x8 Bl = __builtin_bit_cast(f16x8, *(const bf16x8*)(cf + nt*18432 + ks*2048 + 1024 + l*16));
            o[nt] = MFMAH(Aq, Bh, o[nt]);
            o[nt] = MFMAH(Aq, Bl, o[nt]);
        }
    }
    // store out = o * Dinv
    #pragma unroll
    for (int nt = 0; nt < 4; ++nt){
        const size_t rb = (size_t)(rowb + w*16 + lg*4);
        out[(rb + 0)*64 + nt*16 + fq] = o[nt].x * iv0;
        out[(rb + 1)*64 + nt*16 + fq] = o[nt].y * iv1;
        out[(rb + 2)*64 + nt*16 + fq] = o[nt].z * iv2;
        out[(rb + 3)*64 + nt*16 + fq] = o[nt].w * iv3;
    }
}

extern "C" void kernel_launch(void* const* d_in, const int* in_sizes, int n_in,
                              void* d_out, int out_size, void* d_ws, size_t ws_size,
                              hipStream_t stream)
{
    const float* q    = (const float*)d_in[0];
    const float* k    = (const float*)d_in[1];
    const float* v    = (const float*)d_in[2];
    const float* proj = (const float*)d_in[3];
    float* out = (float*)d_out;
    char* ws = (char*)d_ws;

    (void)hipMemsetAsync(ws, 0, WS_ZERO_BYTES, stream);
    prep_proj<<<34, 64, 0, stream>>>(proj, ws);
    k2_ctx<<<dim3(8, 64), 256, 0, stream>>>(k, v, ws);
    prep_ctx<<<2304, 64, 0, stream>>>(ws);
    k3_out<<<2048, 256, 0, stream>>>(q, ws, out);
}